// Round 1
// baseline (241.887 us; speedup 1.0000x reference)
//
#include <hip/hip_runtime.h>
#include <hip/hip_bf16.h>

#define Nn 50000
#define DEG 16
#define IN_F 512
#define HID 128
#define OUT_F 64
#define SLOPE 0.2f

typedef __attribute__((ext_vector_type(8))) short bf16x8;
typedef __attribute__((ext_vector_type(4))) float f32x4;
typedef __attribute__((ext_vector_type(4))) unsigned int u32x4;

__device__ __forceinline__ unsigned short f2bf(float f) {
    return __builtin_bit_cast(unsigned short, __float2bfloat16(f));
}
__device__ __forceinline__ float bf2f(unsigned short u) {
    return __bfloat162float(__builtin_bit_cast(__hip_bfloat16, u));
}

// ---------- prep ----------
// Fold the linear chain: W12 = W1@W2 (bf16, stored transposed [64][512] for
// MFMA B-fragments), u1 = W1@al1, v1 = W1@ar1 (fp32), c2 = b1@W2 (fp32).
// One wave per k-row of W1 (512 waves = 128 blocks); lane = output col.
__global__ void __launch_bounds__(256) prep_kernel(
        const float* __restrict__ W1, const float* __restrict__ W2,
        const float* __restrict__ al1, const float* __restrict__ ar1,
        const float* __restrict__ b1, const int* __restrict__ row_ptr,
        unsigned short* __restrict__ w12t, float* __restrict__ uv,
        float* __restrict__ c2v, int* __restrict__ flag64) {
    const int tid = threadIdx.x;
    const int lane = tid & 63;
    const int w = tid >> 6;
    const int k = blockIdx.x * 4 + w;          // 0..511
    if (blockIdx.x == 0 && tid == 0) {
        // int32 layout: row_ptr words = [0,16,32,...]; int64: [0,0,16,0,...]
        *flag64 = (row_ptr[1] == DEG) ? 0 : 1;
    }
    const float* w1row = W1 + (size_t)k * HID;

    // W12[k][lane] = sum_j W1[k][j] * W2[j][lane]   (lane = 0..63)
    float acc = 0.f;
    #pragma unroll 8
    for (int j = 0; j < HID; ++j)
        acc += w1row[j] * W2[j * OUT_F + lane];
    w12t[(size_t)lane * IN_F + k] = f2bf(acc);     // B^T layout [col][k]

    // u1[k], v1[k]: 128-dot distributed over 64 lanes (2 j's each)
    float pu = w1row[lane] * al1[lane] + w1row[lane + 64] * al1[lane + 64];
    float pv = w1row[lane] * ar1[lane] + w1row[lane + 64] * ar1[lane + 64];
    #pragma unroll
    for (int m = 1; m < 64; m <<= 1) {
        pu += __shfl_xor(pu, m);
        pv += __shfl_xor(pv, m);
    }
    if (lane == 0) { uv[k] = pu; uv[IN_F + k] = pv; }

    // c2 = b1 @ W2 (64 fp32), computed once by block 0 / wave 0
    if (blockIdx.x == 0 && w == 0) {
        float cacc = 0.f;
        #pragma unroll 8
        for (int j = 0; j < HID; ++j) cacc += b1[j] * W2[j * OUT_F + lane];
        c2v[lane] = cacc;
    }
}

// ---------- layer-1: g = x @ W12 (bf16 MFMA) + fp32 el1/er1 row dots ----------
// No LDS, no barriers: A rows are wave-private (16 rows via ln), B = W12^T
// (64 KB) streamed per-fragment from L2 (hot everywhere). el/er accumulate in
// fp32 from the SAME fp32 A registers (exact vs reference) and reduce over the
// q sub-lanes. Wave tile 16x64, NT=4, K=512.
template<int K>
__global__ void __launch_bounds__(256) gemm1_direct(
        const float* __restrict__ Af, const unsigned short* __restrict__ w12t,
        const float* __restrict__ uv,
        unsigned short* __restrict__ G, float* __restrict__ el,
        float* __restrict__ er, int M) {
    const int tid  = threadIdx.x;
    const int lane = tid & 63;
    const int w    = tid >> 6;
    const int ln   = lane & 15, q = lane >> 4;
    const int mb   = blockIdx.x * 64 + w * 16;

    int m0 = mb + ln; if (m0 > M - 1) m0 = M - 1;
    const float* a0p = Af + (size_t)m0 * K;

    f32x4 acc[4] = {};
    float sl = 0.f, sr = 0.f;

    #pragma unroll 4
    for (int ks = 0; ks < K / 32; ++ks) {
        const int kk = ks * 32 + q * 8;
        f32x4 ap0 = *(const f32x4*)(a0p + kk);
        f32x4 ap1 = *(const f32x4*)(a0p + kk + 4);
        f32x4 u0  = *(const f32x4*)(uv + kk);
        f32x4 u1_ = *(const f32x4*)(uv + kk + 4);
        f32x4 v0  = *(const f32x4*)(uv + K + kk);
        f32x4 v1_ = *(const f32x4*)(uv + K + kk + 4);
        bf16x8 af;
        #pragma unroll
        for (int jj = 0; jj < 4; ++jj) {
            af[jj]     = (short)f2bf(ap0[jj]);
            af[jj + 4] = (short)f2bf(ap1[jj]);
            sl += ap0[jj] * u0[jj] + ap1[jj] * u1_[jj];
            sr += ap0[jj] * v0[jj] + ap1[jj] * v1_[jj];
        }
        #pragma unroll
        for (int nt = 0; nt < 4; ++nt) {
            bf16x8 bfr = *(const bf16x8*)&w12t[(size_t)(nt * 16 + ln) * K + kk];
            acc[nt] = __builtin_amdgcn_mfma_f32_16x16x32_bf16(af, bfr, acc[nt], 0, 0, 0);
        }
    }

    // el/er: row = mb + ln, k-parts live in the 4 q sub-lanes
    sl += __shfl_xor(sl, 16); sl += __shfl_xor(sl, 32);
    sr += __shfl_xor(sr, 16); sr += __shfl_xor(sr, 32);
    if (q == 0 && mb + ln < M) { el[mb + ln] = sl; er[mb + ln] = sr; }

    // D layout: col = ln, row = q*4 + r
    #pragma unroll
    for (int r = 0; r < 4; ++r) {
        int grow = mb + q * 4 + r;
        if (grow < M) {
            #pragma unroll
            for (int nt = 0; nt < 4; ++nt)
                G[(size_t)grow * OUT_F + nt * 16 + ln] = f2bf(acc[nt][r]);
        }
    }
}

// ---------- aggregation (both layers): softmax + 128B-row gather ----------
// 16-lane group per node (16 nodes / 256-thread block, no LDS, no barriers).
// Softmax over the group's 16 edges; gather: half = ln>>3 handles edge jj+half,
// lane covers 16B (8 bf16 cols) -> 8 iterations of 16B loads, then a cross-half
// shfl-add completes the 16-edge sum. MODE 0: +c2, write bf16 h2 + el2/er2.
// MODE 1: +bias2, write fp32 out.
template<int MODE>
__global__ void __launch_bounds__(256) agg_k(
        const int* __restrict__ col, const int* __restrict__ flag64,
        const float* __restrict__ el, const float* __restrict__ er,
        const unsigned short* __restrict__ Hs, const float* __restrict__ addv,
        const float* __restrict__ alv, const float* __restrict__ arv,
        unsigned short* __restrict__ Ho, float* __restrict__ elo,
        float* __restrict__ ero, float* __restrict__ Fo) {
    const int tid  = threadIdx.x;
    const int lane = tid & 63;
    const int w    = tid >> 6;
    const int ln   = lane & 15, q = lane >> 4;
    const int node = blockIdx.x * 16 + w * 4 + q;
    const int use64 = *flag64;

    // ---- softmax over the node's 16 edges (lane ln = edge) ----
    int e   = node * DEG + ln;
    int src = use64 ? (int)((const long long*)col)[e] : col[e];
    float sc = el[node] + er[src];
    sc = sc >= 0.f ? sc : SLOPE * sc;
    float mx = sc;
    #pragma unroll
    for (int m = 1; m < 16; m <<= 1) mx = fmaxf(mx, __shfl_xor(mx, m, 16));
    float ex = __expf(sc - mx);
    float sm = ex;
    #pragma unroll
    for (int m = 1; m < 16; m <<= 1) sm += __shfl_xor(sm, m, 16);
    float alpha = ex / sm;

    // ---- gather: 2 edges in parallel, 8 lanes x 16B per row ----
    const int half = ln >> 3, cc = ln & 7;
    float a[8] = {};
    #pragma unroll
    for (int jj = 0; jj < DEG; jj += 2) {
        int   sj = __shfl(src, jj + half, 16);
        float aj = __shfl(alpha, jj + half, 16);
        bf16x8 hv = *(const bf16x8*)&Hs[(size_t)sj * OUT_F + cc * 8];
        #pragma unroll
        for (int c = 0; c < 8; ++c)
            a[c] += aj * bf2f((unsigned short)hv[c]);
    }
    #pragma unroll
    for (int c = 0; c < 8; ++c) {
        a[c] += __shfl_xor(a[c], 8, 16);       // combine the two edge-halves
        a[c] += addv[cc * 8 + c];
    }

    if (MODE == 0) {
        // el2/er2 from fp32 h2 (pre-quantization), reduce over the 8 cc lanes
        float pl = 0.f, pr = 0.f;
        #pragma unroll
        for (int c = 0; c < 8; ++c) {
            pl += a[c] * alv[cc * 8 + c];
            pr += a[c] * arv[cc * 8 + c];
        }
        #pragma unroll
        for (int m = 1; m < 8; m <<= 1) {
            pl += __shfl_xor(pl, m, 16);
            pr += __shfl_xor(pr, m, 16);
        }
        if (ln == 0) { elo[node] = pl; ero[node] = pr; }
        if (half == 0) {
            unsigned int pk[4];
            #pragma unroll
            for (int c = 0; c < 4; ++c)
                pk[c] = (unsigned int)f2bf(a[2 * c]) |
                        ((unsigned int)f2bf(a[2 * c + 1]) << 16);
            *(u32x4*)&Ho[(size_t)node * OUT_F + cc * 8] = *(u32x4*)pk;
        }
    } else {
        if (half == 0) {
            f32x4 o0, o1;
            #pragma unroll
            for (int c = 0; c < 4; ++c) { o0[c] = a[c]; o1[c] = a[c + 4]; }
            *(f32x4*)&Fo[(size_t)node * OUT_F + cc * 8]     = o0;
            *(f32x4*)&Fo[(size_t)node * OUT_F + cc * 8 + 4] = o1;
        }
    }
}

extern "C" void kernel_launch(void* const* d_in, const int* in_sizes, int n_in,
                              void* d_out, int out_size, void* d_ws, size_t ws_size,
                              hipStream_t stream) {
    const int*   row_ptr = (const int*)d_in[0];
    const int*   col_idx = (const int*)d_in[1];
    const float* x   = (const float*)d_in[2];
    const float* W1  = (const float*)d_in[3];
    const float* al1 = (const float*)d_in[4];
    const float* ar1 = (const float*)d_in[5];
    const float* b1  = (const float*)d_in[6];
    const float* W2  = (const float*)d_in[7];
    const float* al2 = (const float*)d_in[8];
    const float* ar2 = (const float*)d_in[9];
    const float* b2  = (const float*)d_in[10];
    float* out = (float*)d_out;

    float* ws = (float*)d_ws;
    unsigned short* g   = (unsigned short*)ws;                 // N*64 bf16
    unsigned short* h2b = (unsigned short*)(ws + 1600000);     // N*64 bf16
    float* el1 = ws + 3200000;
    float* er1 = ws + 3250000;
    float* el2 = ws + 3300000;
    float* er2 = ws + 3350000;
    unsigned short* w12t = (unsigned short*)(ws + 3400000);    // 64*512 bf16
    float* uv  = ws + 3420000;                                 // u1[512], v1[512]
    float* c2v = ws + 3421024;                                 // 64
    int* flag64 = (int*)(ws + 3421100);

    prep_kernel<<<128, 256, 0, stream>>>(
        W1, W2, al1, ar1, b1, row_ptr, w12t, uv, c2v, flag64);

    gemm1_direct<IN_F><<<(Nn + 63) / 64, 256, 0, stream>>>(
        x, w12t, uv, g, el1, er1, Nn);

    agg_k<0><<<Nn / 16, 256, 0, stream>>>(
        col_idx, flag64, el1, er1, g, c2v, al2, ar2, h2b, el2, er2, nullptr);

    agg_k<1><<<Nn / 16, 256, 0, stream>>>(
        col_idx, flag64, el2, er2, h2b, b2, nullptr, nullptr,
        nullptr, nullptr, nullptr, out);
}

// Round 2
// 232.345 us; speedup vs baseline: 1.0411x; 1.0411x over previous
//
#include <hip/hip_runtime.h>
#include <hip/hip_bf16.h>

#define Nn 50000
#define DEG 16
#define IN_F 512
#define HID 128
#define OUT_F 64
#define SLOPE 0.2f

typedef __attribute__((ext_vector_type(8))) short bf16x8;
typedef __attribute__((ext_vector_type(4))) float f32x4;
typedef __attribute__((ext_vector_type(4))) unsigned int u32x4;

__device__ __forceinline__ unsigned short f2bf(float f) {
    return __builtin_bit_cast(unsigned short, __float2bfloat16(f));
}
__device__ __forceinline__ float bf2f(unsigned short u) {
    return __bfloat162float(__builtin_bit_cast(__hip_bfloat16, u));
}

// ---------- prep ----------
// Fold the linear chain: W12 = W1@W2 (bf16, stored transposed [64][512] for
// MFMA B-fragments), u1 = W1@al1, v1 = W1@ar1 (fp32), c2 = b1@W2 (fp32).
// One wave per k-row of W1 (512 waves = 128 blocks); lane = output col.
__global__ void __launch_bounds__(256) prep_kernel(
        const float* __restrict__ W1, const float* __restrict__ W2,
        const float* __restrict__ al1, const float* __restrict__ ar1,
        const float* __restrict__ b1, const int* __restrict__ row_ptr,
        unsigned short* __restrict__ w12t, float* __restrict__ uv,
        float* __restrict__ c2v, int* __restrict__ flag64) {
    const int tid = threadIdx.x;
    const int lane = tid & 63;
    const int w = tid >> 6;
    const int k = blockIdx.x * 4 + w;          // 0..511
    if (blockIdx.x == 0 && tid == 0) {
        // int32 layout: row_ptr words = [0,16,32,...]; int64: [0,0,16,0,...]
        *flag64 = (row_ptr[1] == DEG) ? 0 : 1;
    }
    const float* w1row = W1 + (size_t)k * HID;

    // W12[k][lane] = sum_j W1[k][j] * W2[j][lane]   (lane = 0..63)
    float acc = 0.f;
    #pragma unroll 8
    for (int j = 0; j < HID; ++j)
        acc += w1row[j] * W2[j * OUT_F + lane];
    w12t[(size_t)lane * IN_F + k] = f2bf(acc);     // B^T layout [col][k]

    // u1[k], v1[k]: 128-dot distributed over 64 lanes (2 j's each)
    float pu = w1row[lane] * al1[lane] + w1row[lane + 64] * al1[lane + 64];
    float pv = w1row[lane] * ar1[lane] + w1row[lane + 64] * ar1[lane + 64];
    #pragma unroll
    for (int m = 1; m < 64; m <<= 1) {
        pu += __shfl_xor(pu, m);
        pv += __shfl_xor(pv, m);
    }
    if (lane == 0) { uv[k] = pu; uv[IN_F + k] = pv; }

    // c2 = b1 @ W2 (64 fp32), computed once by block 0 / wave 0
    if (blockIdx.x == 0 && w == 0) {
        float cacc = 0.f;
        #pragma unroll 8
        for (int j = 0; j < HID; ++j) cacc += b1[j] * W2[j * OUT_F + lane];
        c2v[lane] = cacc;
    }
}

// ---------- layer-1: g = x @ W12, 4-way split-K for occupancy ----------
// Block = 16 rows, 4 waves each owning a K=128 slice -> grid 3125, 12500
// waves (~4x the full-K version whose 26% occupancy left every pipe idle).
// All 8 A-loads (the only L3/HBM-latency loads) hoisted before the MFMA
// phase. Partials reduced through padded LDS [w][col][row] (stride 20:
// 16B-aligned for b128, spreads banks). el/er fp32 dots fold in the same
// reduction. No bounds checks needed: 50000 % 16 == 0.
template<int K>
__global__ void __launch_bounds__(256) gemm1_splitk(
        const float* __restrict__ Af, const unsigned short* __restrict__ w12t,
        const float* __restrict__ uv,
        unsigned short* __restrict__ G, float* __restrict__ el,
        float* __restrict__ er, int M) {
    constexpr int KW = K / 4;                  // 128 k's per wave
    constexpr int RS = 20;                     // padded row stride (floats)
    __shared__ float red[4][64][RS];           // 20 KB wave partials
    __shared__ float redl[4][16];
    __shared__ float redr[4][16];

    const int tid  = threadIdx.x;
    const int lane = tid & 63;
    const int w    = tid >> 6;
    const int ln   = lane & 15, q = lane >> 4;
    const int mb   = blockIdx.x * 16;

    int m0 = mb + ln; if (m0 > M - 1) m0 = M - 1;
    const float* a0p = Af + (size_t)m0 * K + w * KW + q * 8;
    const float* up  = uv + w * KW + q * 8;
    const float* vp  = uv + K + w * KW + q * 8;

    // hoist all A loads: 8 independent VMEM ops in flight
    f32x4 ap[4][2];
    #pragma unroll
    for (int ks = 0; ks < 4; ++ks) {
        ap[ks][0] = *(const f32x4*)(a0p + ks * 32);
        ap[ks][1] = *(const f32x4*)(a0p + ks * 32 + 4);
    }

    f32x4 acc[4] = {};
    float sl = 0.f, sr = 0.f;
    #pragma unroll
    for (int ks = 0; ks < 4; ++ks) {
        f32x4 u0 = *(const f32x4*)(up + ks * 32);
        f32x4 u1 = *(const f32x4*)(up + ks * 32 + 4);
        f32x4 v0 = *(const f32x4*)(vp + ks * 32);
        f32x4 v1 = *(const f32x4*)(vp + ks * 32 + 4);
        bf16x8 af;
        #pragma unroll
        for (int jj = 0; jj < 4; ++jj) {
            af[jj]     = (short)f2bf(ap[ks][0][jj]);
            af[jj + 4] = (short)f2bf(ap[ks][1][jj]);
            sl += ap[ks][0][jj] * u0[jj] + ap[ks][1][jj] * u1[jj];
            sr += ap[ks][0][jj] * v0[jj] + ap[ks][1][jj] * v1[jj];
        }
        #pragma unroll
        for (int nt = 0; nt < 4; ++nt) {
            bf16x8 bfr = *(const bf16x8*)
                &w12t[(size_t)(nt * 16 + ln) * K + w * KW + ks * 32 + q * 8];
            acc[nt] = __builtin_amdgcn_mfma_f32_16x16x32_bf16(af, bfr, acc[nt], 0, 0, 0);
        }
    }

    // stash partials: D layout col = ln', row = q*4 + r  ->  [w][col][row]
    #pragma unroll
    for (int nt = 0; nt < 4; ++nt)
        *(f32x4*)&red[w][nt * 16 + ln][q * 4] = acc[nt];

    // el/er: row = ln, k-parts in the 4 q sub-lanes, then across waves
    sl += __shfl_xor(sl, 16); sl += __shfl_xor(sl, 32);
    sr += __shfl_xor(sr, 16); sr += __shfl_xor(sr, 32);
    if (q == 0) { redl[w][ln] = sl; redr[w][ln] = sr; }
    __syncthreads();

    // cross-wave reduce + bf16 store: thread -> col = tid&63, rows r0..r0+3
    const int c  = tid & 63;
    const int r0 = (tid >> 6) * 4;
    f32x4 s = *(const f32x4*)&red[0][c][r0];
    #pragma unroll
    for (int ww = 1; ww < 4; ++ww) {
        f32x4 p = *(const f32x4*)&red[ww][c][r0];
        s += p;
    }
    #pragma unroll
    for (int j = 0; j < 4; ++j)
        G[(size_t)(mb + r0 + j) * OUT_F + c] = f2bf(s[j]);

    if (tid < 16) {
        el[mb + tid] = redl[0][tid] + redl[1][tid] + redl[2][tid] + redl[3][tid];
        er[mb + tid] = redr[0][tid] + redr[1][tid] + redr[2][tid] + redr[3][tid];
    }
}

// ---------- aggregation (both layers): softmax + 128B-row gather ----------
// 16-lane group per node (16 nodes / 256-thread block, no LDS, no barriers).
// Softmax over the group's 16 edges; gather: half = ln>>3 handles edge jj+half,
// lane covers 16B (8 bf16 cols) -> 8 iterations of 16B loads, then a cross-half
// shfl-add completes the 16-edge sum. MODE 0: +c2, write bf16 h2 + el2/er2.
// MODE 1: +bias2, write fp32 out.
template<int MODE>
__global__ void __launch_bounds__(256) agg_k(
        const int* __restrict__ col, const int* __restrict__ flag64,
        const float* __restrict__ el, const float* __restrict__ er,
        const unsigned short* __restrict__ Hs, const float* __restrict__ addv,
        const float* __restrict__ alv, const float* __restrict__ arv,
        unsigned short* __restrict__ Ho, float* __restrict__ elo,
        float* __restrict__ ero, float* __restrict__ Fo) {
    const int tid  = threadIdx.x;
    const int lane = tid & 63;
    const int w    = tid >> 6;
    const int ln   = lane & 15, q = lane >> 4;
    const int node = blockIdx.x * 16 + w * 4 + q;
    const int use64 = *flag64;

    // ---- softmax over the node's 16 edges (lane ln = edge) ----
    int e   = node * DEG + ln;
    int src = use64 ? (int)((const long long*)col)[e] : col[e];
    float sc = el[node] + er[src];
    sc = sc >= 0.f ? sc : SLOPE * sc;
    float mx = sc;
    #pragma unroll
    for (int m = 1; m < 16; m <<= 1) mx = fmaxf(mx, __shfl_xor(mx, m, 16));
    float ex = __expf(sc - mx);
    float sm = ex;
    #pragma unroll
    for (int m = 1; m < 16; m <<= 1) sm += __shfl_xor(sm, m, 16);
    float alpha = ex / sm;

    // ---- gather: 2 edges in parallel, 8 lanes x 16B per row ----
    const int half = ln >> 3, cc = ln & 7;
    float a[8] = {};
    #pragma unroll
    for (int jj = 0; jj < DEG; jj += 2) {
        int   sj = __shfl(src, jj + half, 16);
        float aj = __shfl(alpha, jj + half, 16);
        bf16x8 hv = *(const bf16x8*)&Hs[(size_t)sj * OUT_F + cc * 8];
        #pragma unroll
        for (int c = 0; c < 8; ++c)
            a[c] += aj * bf2f((unsigned short)hv[c]);
    }
    #pragma unroll
    for (int c = 0; c < 8; ++c) {
        a[c] += __shfl_xor(a[c], 8, 16);       // combine the two edge-halves
        a[c] += addv[cc * 8 + c];
    }

    if (MODE == 0) {
        // el2/er2 from fp32 h2 (pre-quantization), reduce over the 8 cc lanes
        float pl = 0.f, pr = 0.f;
        #pragma unroll
        for (int c = 0; c < 8; ++c) {
            pl += a[c] * alv[cc * 8 + c];
            pr += a[c] * arv[cc * 8 + c];
        }
        #pragma unroll
        for (int m = 1; m < 8; m <<= 1) {
            pl += __shfl_xor(pl, m, 16);
            pr += __shfl_xor(pr, m, 16);
        }
        if (ln == 0) { elo[node] = pl; ero[node] = pr; }
        if (half == 0) {
            unsigned int pk[4];
            #pragma unroll
            for (int c = 0; c < 4; ++c)
                pk[c] = (unsigned int)f2bf(a[2 * c]) |
                        ((unsigned int)f2bf(a[2 * c + 1]) << 16);
            *(u32x4*)&Ho[(size_t)node * OUT_F + cc * 8] = *(u32x4*)pk;
        }
    } else {
        if (half == 0) {
            f32x4 o0, o1;
            #pragma unroll
            for (int c = 0; c < 4; ++c) { o0[c] = a[c]; o1[c] = a[c + 4]; }
            *(f32x4*)&Fo[(size_t)node * OUT_F + cc * 8]     = o0;
            *(f32x4*)&Fo[(size_t)node * OUT_F + cc * 8 + 4] = o1;
        }
    }
}

extern "C" void kernel_launch(void* const* d_in, const int* in_sizes, int n_in,
                              void* d_out, int out_size, void* d_ws, size_t ws_size,
                              hipStream_t stream) {
    const int*   row_ptr = (const int*)d_in[0];
    const int*   col_idx = (const int*)d_in[1];
    const float* x   = (const float*)d_in[2];
    const float* W1  = (const float*)d_in[3];
    const float* al1 = (const float*)d_in[4];
    const float* ar1 = (const float*)d_in[5];
    const float* b1  = (const float*)d_in[6];
    const float* W2  = (const float*)d_in[7];
    const float* al2 = (const float*)d_in[8];
    const float* ar2 = (const float*)d_in[9];
    const float* b2  = (const float*)d_in[10];
    float* out = (float*)d_out;

    float* ws = (float*)d_ws;
    unsigned short* g   = (unsigned short*)ws;                 // N*64 bf16
    unsigned short* h2b = (unsigned short*)(ws + 1600000);     // N*64 bf16
    float* el1 = ws + 3200000;
    float* er1 = ws + 3250000;
    float* el2 = ws + 3300000;
    float* er2 = ws + 3350000;
    unsigned short* w12t = (unsigned short*)(ws + 3400000);    // 64*512 bf16
    float* uv  = ws + 3420000;                                 // u1[512], v1[512]
    float* c2v = ws + 3421024;                                 // 64
    int* flag64 = (int*)(ws + 3421100);

    prep_kernel<<<128, 256, 0, stream>>>(
        W1, W2, al1, ar1, b1, row_ptr, w12t, uv, c2v, flag64);

    gemm1_splitk<IN_F><<<Nn / 16, 256, 0, stream>>>(
        x, w12t, uv, g, el1, er1, Nn);

    agg_k<0><<<Nn / 16, 256, 0, stream>>>(
        col_idx, flag64, el1, er1, g, c2v, al2, ar2, h2b, el2, er2, nullptr);

    agg_k<1><<<Nn / 16, 256, 0, stream>>>(
        col_idx, flag64, el2, er2, h2b, b2, nullptr, nullptr,
        nullptr, nullptr, nullptr, out);
}